// Round 1
// baseline (5015.670 us; speedup 1.0000x reference)
//
#include <hip/hip_runtime.h>

// GIN: 5 layers, DIM=10. Identity: (x+agg)@W1 = x@W1 + segsum((x@W1)[src]).
// R8: replace edge-parallel segmented-scan (kA) + node reconstruct (kB) + full
// by-node sort (k_p2) with ONE fused per-bucket kernel: block owns 1024 nodes,
// accumulates agg in LDS via native ds_add_f32 (stride 11 -> coprime bank mix),
// then runs the MLP for its nodes after one barrier. kA was VALU+DS issue-bound
// (38.5% VALUBusy, ~78 ds_bpermute + ~220 VALU per 128-edge wave); LDS atomics
// cost ~10 ds + ~10 VALU per 64-edge wave-batch instead. Also kills the global
// agg/carry round-trip and the entire k_p2 dispatch.

#define SENTINEL 0xFFFFFFFFu

__device__ __forceinline__ unsigned short f2bf(float f) {
    unsigned b = __float_as_uint(f);
    b += 0x7fffu + ((b >> 16) & 1u);   // round-to-nearest-even
    return (unsigned short)(b >> 16);
}
__device__ __forceinline__ float bflo(unsigned u) { return __uint_as_float(u << 16); }
__device__ __forceinline__ float bfhi(unsigned u) { return __uint_as_float(u & 0xffff0000u); }

// LDS float add, guaranteed native ds_add_f32 (workgroup scope, relaxed).
__device__ __forceinline__ void ldsAdd(float* a, float v) {
    __hip_atomic_fetch_add(a, v, __ATOMIC_RELAXED, __HIP_MEMORY_SCOPE_WORKGROUP);
}

// ---------------- Layer-1: y = h @ W1_1 (bf16 rows, 8 uints/row) ----------------
__global__ void k1_hw1_bf16(const float* __restrict__ h, const float* __restrict__ W1,
                            unsigned* __restrict__ y, int N) {
    __shared__ float sW[640];
    for (int i = threadIdx.x; i < 640; i += blockDim.x) sW[i] = W1[i];
    __syncthreads();
    int n = blockIdx.x * blockDim.x + threadIdx.x;
    if (n >= N) return;
    const float* hr = h + (size_t)n * 64;
    float acc[10];
#pragma unroll
    for (int j = 0; j < 10; j++) acc[j] = 0.f;
#pragma unroll 4
    for (int k = 0; k < 64; k += 4) {
        float4 hv = *(const float4*)(hr + k);
#pragma unroll
        for (int j = 0; j < 10; j++) {
            acc[j] += hv.x * sW[(k + 0) * 10 + j];
            acc[j] += hv.y * sW[(k + 1) * 10 + j];
            acc[j] += hv.z * sW[(k + 2) * 10 + j];
            acc[j] += hv.w * sW[(k + 3) * 10 + j];
        }
    }
    unsigned r0 = (unsigned)f2bf(acc[0]) | ((unsigned)f2bf(acc[1]) << 16);
    unsigned r1 = (unsigned)f2bf(acc[2]) | ((unsigned)f2bf(acc[3]) << 16);
    unsigned r2 = (unsigned)f2bf(acc[4]) | ((unsigned)f2bf(acc[5]) << 16);
    unsigned r3 = (unsigned)f2bf(acc[6]) | ((unsigned)f2bf(acc[7]) << 16);
    unsigned r4 = (unsigned)f2bf(acc[8]) | ((unsigned)f2bf(acc[9]) << 16);
    unsigned* yr = y + (size_t)n * 8;
    *(uint4*)yr = make_uint4(r0, r1, r2, r3);
    yr[4] = r4;
}

// f32 variant for the fallback path (16-float rows)
__global__ void k1_hw1_f32(const float* __restrict__ h, const float* __restrict__ W1,
                           float* __restrict__ y, int N) {
    __shared__ float sW[640];
    for (int i = threadIdx.x; i < 640; i += blockDim.x) sW[i] = W1[i];
    __syncthreads();
    int n = blockIdx.x * blockDim.x + threadIdx.x;
    if (n >= N) return;
    const float* hr = h + (size_t)n * 64;
    float acc[10];
#pragma unroll
    for (int j = 0; j < 10; j++) acc[j] = 0.f;
#pragma unroll 4
    for (int k = 0; k < 64; k += 4) {
        float4 hv = *(const float4*)(hr + k);
#pragma unroll
        for (int j = 0; j < 10; j++) {
            acc[j] += hv.x * sW[(k + 0) * 10 + j];
            acc[j] += hv.y * sW[(k + 1) * 10 + j];
            acc[j] += hv.z * sW[(k + 2) * 10 + j];
            acc[j] += hv.w * sW[(k + 3) * 10 + j];
        }
    }
    float* yr = y + (size_t)n * 16;
#pragma unroll
    for (int j = 0; j < 10; j++) yr[j] = acc[j];
}

// =================== CSR build: bucket split (dst>>10, 512 buckets) ===================
__global__ void k_bhist(const int* __restrict__ dst, unsigned* __restrict__ bucket_cnt,
                        int E) {
    __shared__ unsigned h[512];
    int t = threadIdx.x;
    h[t] = 0; h[t + 256] = 0;
    __syncthreads();
    int stride = gridDim.x * blockDim.x;
    for (int e = blockIdx.x * blockDim.x + t; e < E; e += stride)
        atomicAdd(&h[(unsigned)dst[e] >> 10], 1u);
    __syncthreads();
    if (h[t]) atomicAdd(&bucket_cnt[t], h[t]);
    if (h[t + 256]) atomicAdd(&bucket_cnt[t + 256], h[t + 256]);
}

__global__ void k_bscan(const unsigned* __restrict__ bucket_cnt,
                        unsigned* __restrict__ bbase, unsigned* __restrict__ bcur, int B) {
    __shared__ unsigned s[512];
    int t = threadIdx.x;
    unsigned v = (t < B) ? bucket_cnt[t] : 0u;
    s[t] = v;
    __syncthreads();
    for (int off = 1; off < 512; off <<= 1) {
        unsigned u = (t >= off) ? s[t - off] : 0u;
        __syncthreads();
        s[t] += u;
        __syncthreads();
    }
    unsigned excl = s[t] - v;
    if (t < B) { bbase[t] = excl; bcur[t] = excl; }
    if (t == B - 1) bbase[B] = s[t];
}

__global__ __launch_bounds__(1024) void k_bscatter2(
        const int* __restrict__ src, const int* __restrict__ dst,
        unsigned* __restrict__ bcur, unsigned* __restrict__ pairs,
        int E, int nblocks) {
    __shared__ unsigned cnt[512];
    int t = threadIdx.x;
    int per = (E + nblocks - 1) / nblocks;
    int beg = blockIdx.x * per;
    int end = beg + per; if (end > E) end = E;
    if (beg >= E) return;
    if (t < 512) cnt[t] = 0;
    __syncthreads();
    for (int e = beg + t; e < end; e += 1024)
        atomicAdd(&cnt[(unsigned)dst[e] >> 10], 1u);
    __syncthreads();
    unsigned c = 0, base = 0;
    if (t < 512) { c = cnt[t]; if (c) base = atomicAdd(&bcur[t], c); }
    __syncthreads();
    if (t < 512) cnt[t] = base;
    __syncthreads();
    for (int e = beg + t; e < end; e += 1024) {
        unsigned d = (unsigned)dst[e];
        unsigned pos = atomicAdd(&cnt[d >> 10], 1u);
        pairs[pos] = ((unsigned)src[e] << 10) | (d & 1023u);
    }
}

// k_p2 kept for the R4 fallback path only (packed=0 -> plain src edges + row_start)
__global__ __launch_bounds__(1024) void k_p2(
        const unsigned* __restrict__ pairs, const unsigned* __restrict__ bbase,
        unsigned* __restrict__ edges, unsigned* __restrict__ row_start,
        int N, int B, int E, int packed) {
    __shared__ unsigned cnt[1024], scn[1024], cur[1024];
    int t = threadIdx.x, b = blockIdx.x;
    unsigned beg = bbase[b], end = bbase[b + 1];
    cnt[t] = 0;
    __syncthreads();
    for (unsigned e = beg + t; e < end; e += 1024)
        atomicAdd(&cnt[pairs[e] & 1023u], 1u);
    __syncthreads();
    unsigned v = cnt[t];
    scn[t] = v;
    __syncthreads();
    for (int off = 1; off < 1024; off <<= 1) {
        unsigned u = (t >= off) ? scn[t - off] : 0u;
        __syncthreads();
        scn[t] += u;
        __syncthreads();
    }
    unsigned excl = scn[t] - v;
    int node = (b << 10) + t;
    if (node < N) row_start[node] = beg + excl;
    if (b == B - 1 && t == 0) row_start[N] = (unsigned)E;
    cur[t] = beg + excl;
    __syncthreads();
    for (unsigned e = beg + t; e < end; e += 1024) {
        unsigned pv = pairs[e];
        unsigned pos = atomicAdd(&cur[pv & 1023u], 1u);
        edges[pos] = packed ? pv : (pv >> 10);
    }
}

// =================== R8 hot phase: fused per-bucket aggregate + MLP ===================
// Block b owns nodes [b*1024, b*1024+1024). Phase 1: zero LDS agg + stage weights.
// Phase 2: stream the bucket's edge range; per edge gather bf16 y[src], 10x
// ds_add_f32 into agg[dst_lo] (stride 11 floats: 11 coprime 32 -> full bank mix).
// Phase 3: per-node MLP from LDS agg + self row, graph-sum atomics, write y_next.
__global__ __launch_bounds__(1024, 8) void kL_fused(
        const unsigned* __restrict__ yin, unsigned* __restrict__ yout,
        const unsigned* __restrict__ pairs, const unsigned* __restrict__ bbase,
        const float* __restrict__ b1, const float* __restrict__ W2,
        const float* __restrict__ b2, const float* __restrict__ l,
        const float* __restrict__ W1n,
        const int* __restrict__ node_graph, float* __restrict__ gacc,
        int N, int last) {
    __shared__ float sAgg[1024 * 11];
    __shared__ float sW2[100], sW1[100], sb1[10], sb2[10], sl[10];
    int t = threadIdx.x;
    int b = blockIdx.x;
    if (t < 100) sW2[t] = W2[t];
    if (!last && t >= 128 && t < 228) sW1[t - 128] = W1n[t - 128];
    if (t < 10) { sb1[t] = b1[t]; sb2[t] = b2[t]; sl[t] = l[t]; }
#pragma unroll
    for (int i = 0; i < 11; i++) sAgg[i * 1024 + t] = 0.f;
    __syncthreads();

    unsigned beg = bbase[b], end = bbase[b + 1];
    unsigned e = beg + (unsigned)t;
    // 2x unrolled: two independent gathers in flight per iteration
    for (; e + 1024u < end; e += 2048u) {
        unsigned pv0 = pairs[e];
        unsigned pv1 = pairs[e + 1024u];
        const unsigned* p0 = yin + (size_t)(pv0 >> 10) * 8;
        const unsigned* p1 = yin + (size_t)(pv1 >> 10) * 8;
        uint4 qa = *(const uint4*)p0; unsigned qa4 = p0[4];
        uint4 qb = *(const uint4*)p1; unsigned qb4 = p1[4];
        float* a0 = sAgg + (pv0 & 1023u) * 11;
        float* a1 = sAgg + (pv1 & 1023u) * 11;
        ldsAdd(a0 + 0, bflo(qa.x)); ldsAdd(a0 + 1, bfhi(qa.x));
        ldsAdd(a0 + 2, bflo(qa.y)); ldsAdd(a0 + 3, bfhi(qa.y));
        ldsAdd(a0 + 4, bflo(qa.z)); ldsAdd(a0 + 5, bfhi(qa.z));
        ldsAdd(a0 + 6, bflo(qa.w)); ldsAdd(a0 + 7, bfhi(qa.w));
        ldsAdd(a0 + 8, bflo(qa4));  ldsAdd(a0 + 9, bfhi(qa4));
        ldsAdd(a1 + 0, bflo(qb.x)); ldsAdd(a1 + 1, bfhi(qb.x));
        ldsAdd(a1 + 2, bflo(qb.y)); ldsAdd(a1 + 3, bfhi(qb.y));
        ldsAdd(a1 + 4, bflo(qb.z)); ldsAdd(a1 + 5, bfhi(qb.z));
        ldsAdd(a1 + 6, bflo(qb.w)); ldsAdd(a1 + 7, bfhi(qb.w));
        ldsAdd(a1 + 8, bflo(qb4));  ldsAdd(a1 + 9, bfhi(qb4));
    }
    if (e < end) {
        unsigned pv0 = pairs[e];
        const unsigned* p0 = yin + (size_t)(pv0 >> 10) * 8;
        uint4 qa = *(const uint4*)p0; unsigned qa4 = p0[4];
        float* a0 = sAgg + (pv0 & 1023u) * 11;
        ldsAdd(a0 + 0, bflo(qa.x)); ldsAdd(a0 + 1, bfhi(qa.x));
        ldsAdd(a0 + 2, bflo(qa.y)); ldsAdd(a0 + 3, bfhi(qa.y));
        ldsAdd(a0 + 4, bflo(qa.z)); ldsAdd(a0 + 5, bfhi(qa.z));
        ldsAdd(a0 + 6, bflo(qa.w)); ldsAdd(a0 + 7, bfhi(qa.w));
        ldsAdd(a0 + 8, bflo(qa4));  ldsAdd(a0 + 9, bfhi(qa4));
    }
    __syncthreads();

    int n = (b << 10) + t;
    bool valid = n < N;
    int nc = valid ? n : (N - 1);
    const unsigned* yr = yin + (size_t)nc * 8;
    uint4 q = *(const uint4*)yr;
    unsigned q4 = yr[4];
    const float* ag = sAgg + t * 11;
    float acc[10] = {bflo(q.x) + ag[0], bfhi(q.x) + ag[1],
                     bflo(q.y) + ag[2], bfhi(q.y) + ag[3],
                     bflo(q.z) + ag[4], bfhi(q.z) + ag[5],
                     bflo(q.w) + ag[6], bfhi(q.w) + ag[7],
                     bflo(q4)  + ag[8], bfhi(q4)  + ag[9]};

    float z[10], x[10];
#pragma unroll
    for (int j = 0; j < 10; j++) {
        float v = acc[j] + sb1[j];
        z[j] = v > 0.f ? v : 0.f;
    }
#pragma unroll
    for (int j = 0; j < 10; j++) {
        float v = sb2[j];
#pragma unroll
        for (int k = 0; k < 10; k++) v += z[k] * sW2[k * 10 + j];
        x[j] = v > 0.f ? v : 0.f;
    }
    float p = 0.f;
#pragma unroll
    for (int j = 0; j < 10; j++) p += x[j] * sl[j];
    if (!valid) p = 0.f;
    int g = node_graph[nc];

    int g0 = __shfl(g, 0);
    if (__all(g == g0)) {
#pragma unroll
        for (int off = 32; off > 0; off >>= 1) p += __shfl_down(p, off);
        if ((t & 63) == 0) unsafeAtomicAdd(&gacc[g0], p);
    } else {
        if (valid) unsafeAtomicAdd(&gacc[g], p);
    }

    if (!last && valid) {
        float yn[10];
#pragma unroll
        for (int j = 0; j < 10; j++) {
            float v = 0.f;
#pragma unroll
            for (int k = 0; k < 10; k++) v += x[k] * sW1[k * 10 + j];
            yn[j] = v;
        }
        unsigned r0 = (unsigned)f2bf(yn[0]) | ((unsigned)f2bf(yn[1]) << 16);
        unsigned r1 = (unsigned)f2bf(yn[2]) | ((unsigned)f2bf(yn[3]) << 16);
        unsigned r2 = (unsigned)f2bf(yn[4]) | ((unsigned)f2bf(yn[5]) << 16);
        unsigned r3 = (unsigned)f2bf(yn[6]) | ((unsigned)f2bf(yn[7]) << 16);
        unsigned r4 = (unsigned)f2bf(yn[8]) | ((unsigned)f2bf(yn[9]) << 16);
        unsigned* yo = yout + (size_t)n * 8;
        *(uint4*)yo = make_uint4(r0, r1, r2, r3);
        yo[4] = r4;
    }
}

// ---------------- Final: out[g] = sigmoid(gacc[g] / max(count,1)) ----------------
__global__ void k4_final(const float* __restrict__ gacc, const int* __restrict__ node_graph,
                         float* __restrict__ out, int N, int G) {
    int g = blockIdx.x * blockDim.x + threadIdx.x;
    if (g >= G) return;
    int lo = 0, hi = N;
    while (lo < hi) { int m = (lo + hi) >> 1; if (node_graph[m] < g) lo = m + 1; else hi = m; }
    int lo2 = lo, hi2 = N;
    while (lo2 < hi2) { int m = (lo2 + hi2) >> 1; if (node_graph[m] <= g) lo2 = m + 1; else hi2 = m; }
    float c = (float)(hi2 - lo);
    if (c < 1.f) c = 1.f;
    float s = gacc[g] / c;
    out[g] = 1.f / (1.f + __expf(-s));
}

// ============ R4 fallback fused layer (f32 rows, src-only edges) ============
__global__ __launch_bounds__(256) void k_layer(
        const float* __restrict__ yin, float* __restrict__ yout,
        const unsigned* __restrict__ row_start, const unsigned* __restrict__ edges,
        const float* __restrict__ b1, const float* __restrict__ W2,
        const float* __restrict__ b2, const float* __restrict__ l,
        const float* __restrict__ W1n,
        const int* __restrict__ node_graph, float* __restrict__ gacc,
        int N, int last) {
    __shared__ float sW2[100], sW1[100], sb1[10], sb2[10], sl[10];
    int t = threadIdx.x;
    if (t < 100) sW2[t] = W2[t];
    if (!last && t >= 128 && t < 228) sW1[t - 128] = W1n[t - 128];
    if (t < 10) { sb1[t] = b1[t]; sb2[t] = b2[t]; sl[t] = l[t]; }
    __syncthreads();
    int n = blockIdx.x * 256 + t;
    bool valid = n < N;
    int nc = valid ? n : (N - 1);
    const float* yr = yin + (size_t)nc * 16;
    float4 a = *(const float4*)yr;
    float4 b = *(const float4*)(yr + 4);
    float2 c = *(const float2*)(yr + 8);
    float acc[10] = {a.x, a.y, a.z, a.w, b.x, b.y, b.z, b.w, c.x, c.y};
    unsigned beg = 0, end = 0;
    if (valid) { beg = row_start[n]; end = row_start[n + 1]; }
    for (unsigned e = beg; e < end; ++e) {
        unsigned s = edges[e];
        const float* pr = yin + (size_t)s * 16;
        float4 pa = *(const float4*)pr;
        float4 pb = *(const float4*)(pr + 4);
        float2 pc = *(const float2*)(pr + 8);
        acc[0] += pa.x; acc[1] += pa.y; acc[2] += pa.z; acc[3] += pa.w;
        acc[4] += pb.x; acc[5] += pb.y; acc[6] += pb.z; acc[7] += pb.w;
        acc[8] += pc.x; acc[9] += pc.y;
    }
    float z[10], x[10];
#pragma unroll
    for (int j = 0; j < 10; j++) {
        float v = acc[j] + sb1[j];
        z[j] = v > 0.f ? v : 0.f;
    }
#pragma unroll
    for (int j = 0; j < 10; j++) {
        float v = sb2[j];
#pragma unroll
        for (int k = 0; k < 10; k++) v += z[k] * sW2[k * 10 + j];
        x[j] = v > 0.f ? v : 0.f;
    }
    float p = 0.f;
#pragma unroll
    for (int j = 0; j < 10; j++) p += x[j] * sl[j];
    if (!valid) p = 0.f;
    int g = node_graph[nc];
    int g0 = __shfl(g, 0);
    if (__all(g == g0)) {
#pragma unroll
        for (int off = 32; off > 0; off >>= 1) p += __shfl_down(p, off);
        if ((t & 63) == 0) unsafeAtomicAdd(&gacc[g0], p);
    } else {
        if (valid) unsafeAtomicAdd(&gacc[g], p);
    }
    if (!last && valid) {
        float yn[10];
#pragma unroll
        for (int j = 0; j < 10; j++) {
            float v = 0.f;
#pragma unroll
            for (int k = 0; k < 10; k++) v += x[k] * sW1[k * 10 + j];
            yn[j] = v;
        }
        float* yo = yout + (size_t)n * 16;
        *(float4*)yo = make_float4(yn[0], yn[1], yn[2], yn[3]);
        *(float4*)(yo + 4) = make_float4(yn[4], yn[5], yn[6], yn[7]);
        *(float2*)(yo + 8) = make_float2(yn[8], yn[9]);
    }
}

static inline size_t al16(size_t w) { return (w + 15) & ~(size_t)15; }

extern "C" void kernel_launch(void* const* d_in, const int* in_sizes, int n_in,
                              void* d_out, int out_size, void* d_ws, size_t ws_size,
                              hipStream_t stream) {
    const float* h  = (const float*)d_in[0];
    const int* src  = (const int*)d_in[1];
    const int* dst  = (const int*)d_in[2];
    const int* ng   = (const int*)d_in[3];
    int N = in_sizes[3];
    int E = in_sizes[1];
    int G = out_size;

    const float* W1[5]; const float* b1[5]; const float* W2[5]; const float* b2[5]; const float* l[5];
    for (int i = 0; i < 5; i++) {
        W1[i] = (const float*)d_in[4 + i * 5 + 0];
        b1[i] = (const float*)d_in[4 + i * 5 + 1];
        W2[i] = (const float*)d_in[4 + i * 5 + 2];
        b2[i] = (const float*)d_in[4 + i * 5 + 3];
        l[i]  = (const float*)d_in[4 + i * 5 + 4];
    }
    float* out = (float*)d_out;

    int B = (N + 1023) >> 10;

    // R8 layout (4B words): y0[N*8] | y1[N*8] | pairs[E] | bucket_cnt[512]
    //                       | bbase[513] | bcur[512] | gacc[G]
    // pairs live across all 5 layers now (kL re-reads them) -> y1 is separate.
    size_t wY = al16((size_t)N * 8);
    size_t wE = al16((size_t)E);
    size_t need_r8 = (2 * wY + wE + 1537 + al16((size_t)G)) * 4;

    size_t regAB = (size_t)N * 16;
    size_t reg2f = ((size_t)E > regAB) ? (size_t)E : regAB;
    size_t need_r4 = (regAB + reg2f + (size_t)E + (size_t)(N + 1) + 1537 + (size_t)G) * 4;

    if (ws_size >= need_r8 && B <= 512) {
        unsigned* y0 = (unsigned*)d_ws;
        unsigned* y1 = y0 + wY;
        unsigned* pairs = y1 + wY;
        unsigned* bucket_cnt = pairs + wE;
        unsigned* bbase = bucket_cnt + 512;
        unsigned* bcur = bbase + 513;
        float* gacc = (float*)(bcur + 512);

        hipMemsetAsync(bucket_cnt, 0, 512 * 4, stream);
        hipMemsetAsync(gacc, 0, (size_t)G * 4, stream);

        k1_hw1_bf16<<<(N + 255) / 256, 256, 0, stream>>>(h, W1[0], y0, N);

        k_bhist<<<2048, 256, 0, stream>>>(dst, bucket_cnt, E);
        k_bscan<<<1, 512, 0, stream>>>(bucket_cnt, bbase, bcur, B);
        k_bscatter2<<<256, 1024, 0, stream>>>(src, dst, bcur, pairs, E, 256);

        unsigned* ybuf[2] = {y0, y1};
        for (int i = 0; i < 5; i++) {
            kL_fused<<<B, 1024, 0, stream>>>(
                ybuf[i & 1], ybuf[(i + 1) & 1], pairs, bbase,
                b1[i], W2[i], b2[i], l[i], i < 4 ? W1[i + 1] : nullptr,
                ng, gacc, N, i == 4 ? 1 : 0);
        }
        k4_final<<<(G + 255) / 256, 256, 0, stream>>>(gacc, ng, out, N, G);
        return;
    }

    // fallback: R4 path (f32 rows, fused node-parallel layer over full CSR)
    if (ws_size >= need_r4 && B <= 512) {
        float* y0 = (float*)d_ws;
        unsigned* pairs = (unsigned*)(y0 + regAB);
        float* y1 = (float*)pairs;
        unsigned* edges = pairs + reg2f;
        unsigned* row_start = edges + E;
        unsigned* bucket_cnt = row_start + (N + 1);
        unsigned* bbase = bucket_cnt + 512;
        unsigned* bcur = bbase + 513;
        float* gacc = (float*)(bcur + 512);

        hipMemsetAsync(bucket_cnt, 0, 512 * 4, stream);
        hipMemsetAsync(gacc, 0, (size_t)G * 4, stream);

        k1_hw1_f32<<<(N + 255) / 256, 256, 0, stream>>>(h, W1[0], y0, N);
        k_bhist<<<2048, 256, 0, stream>>>(dst, bucket_cnt, E);
        k_bscan<<<1, 512, 0, stream>>>(bucket_cnt, bbase, bcur, B);
        k_bscatter2<<<256, 1024, 0, stream>>>(src, dst, bcur, pairs, E, 256);
        k_p2<<<B, 1024, 0, stream>>>(pairs, bbase, edges, row_start, N, B, E, 0);

        float* ybuf[2] = {y0, y1};
        for (int i = 0; i < 5; i++) {
            k_layer<<<(N + 255) / 256, 256, 0, stream>>>(
                ybuf[i & 1], ybuf[(i + 1) & 1], row_start, edges,
                b1[i], W2[i], b2[i], l[i], i < 4 ? W1[i + 1] : nullptr,
                ng, gacc, N, i == 4 ? 1 : 0);
        }
        k4_final<<<(G + 255) / 256, 256, 0, stream>>>(gacc, ng, out, N, G);
    }
}

// Round 2
// 2829.182 us; speedup vs baseline: 1.7728x; 1.7728x over previous
//
#include <hip/hip_runtime.h>

// GIN: 5 layers, DIM=10. Identity: (x+agg)@W1 = x@W1 + segsum((x@W1)[src]).
// R9: node-parallel fused layer over dst-sorted CSR (from k_p2), bf16 rows.
// Replaces R7's edge-parallel segmented scan (kA, 222us: ~70 ds_bpermute +
// ~220 VALU per 128-edge wave) + carry reconstruct (kB). Same byte stream
// (64MB edges + random 32B row gathers, ~788MB L2-miss/layer) with ~10x less
// issue pressure and zero hot-phase atomics.
// R8 lesson (measured): LDS atomics process ~1 lane per 3.3 cycles per CU --
// 10 ds_add_f32/edge = 899us/layer with VALUBusy 1.5%. Never again.

#define SENTINEL 0xFFFFFFFFu

__device__ __forceinline__ unsigned short f2bf(float f) {
    unsigned b = __float_as_uint(f);
    b += 0x7fffu + ((b >> 16) & 1u);   // round-to-nearest-even
    return (unsigned short)(b >> 16);
}
__device__ __forceinline__ float bflo(unsigned u) { return __uint_as_float(u << 16); }
__device__ __forceinline__ float bfhi(unsigned u) { return __uint_as_float(u & 0xffff0000u); }

// ---------------- Layer-1: y = h @ W1_1 (bf16 rows, 8 uints/row) ----------------
__global__ void k1_hw1_bf16(const float* __restrict__ h, const float* __restrict__ W1,
                            unsigned* __restrict__ y, int N) {
    __shared__ float sW[640];
    for (int i = threadIdx.x; i < 640; i += blockDim.x) sW[i] = W1[i];
    __syncthreads();
    int n = blockIdx.x * blockDim.x + threadIdx.x;
    if (n >= N) return;
    const float* hr = h + (size_t)n * 64;
    float acc[10];
#pragma unroll
    for (int j = 0; j < 10; j++) acc[j] = 0.f;
#pragma unroll 4
    for (int k = 0; k < 64; k += 4) {
        float4 hv = *(const float4*)(hr + k);
#pragma unroll
        for (int j = 0; j < 10; j++) {
            acc[j] += hv.x * sW[(k + 0) * 10 + j];
            acc[j] += hv.y * sW[(k + 1) * 10 + j];
            acc[j] += hv.z * sW[(k + 2) * 10 + j];
            acc[j] += hv.w * sW[(k + 3) * 10 + j];
        }
    }
    unsigned r0 = (unsigned)f2bf(acc[0]) | ((unsigned)f2bf(acc[1]) << 16);
    unsigned r1 = (unsigned)f2bf(acc[2]) | ((unsigned)f2bf(acc[3]) << 16);
    unsigned r2 = (unsigned)f2bf(acc[4]) | ((unsigned)f2bf(acc[5]) << 16);
    unsigned r3 = (unsigned)f2bf(acc[6]) | ((unsigned)f2bf(acc[7]) << 16);
    unsigned r4 = (unsigned)f2bf(acc[8]) | ((unsigned)f2bf(acc[9]) << 16);
    unsigned* yr = y + (size_t)n * 8;
    *(uint4*)yr = make_uint4(r0, r1, r2, r3);
    yr[4] = r4;
}

// f32 variant for the fallback path (16-float rows)
__global__ void k1_hw1_f32(const float* __restrict__ h, const float* __restrict__ W1,
                           float* __restrict__ y, int N) {
    __shared__ float sW[640];
    for (int i = threadIdx.x; i < 640; i += blockDim.x) sW[i] = W1[i];
    __syncthreads();
    int n = blockIdx.x * blockDim.x + threadIdx.x;
    if (n >= N) return;
    const float* hr = h + (size_t)n * 64;
    float acc[10];
#pragma unroll
    for (int j = 0; j < 10; j++) acc[j] = 0.f;
#pragma unroll 4
    for (int k = 0; k < 64; k += 4) {
        float4 hv = *(const float4*)(hr + k);
#pragma unroll
        for (int j = 0; j < 10; j++) {
            acc[j] += hv.x * sW[(k + 0) * 10 + j];
            acc[j] += hv.y * sW[(k + 1) * 10 + j];
            acc[j] += hv.z * sW[(k + 2) * 10 + j];
            acc[j] += hv.w * sW[(k + 3) * 10 + j];
        }
    }
    float* yr = y + (size_t)n * 16;
#pragma unroll
    for (int j = 0; j < 10; j++) yr[j] = acc[j];
}

// =================== CSR build: bucket split (dst>>10, 512 buckets) ===================
__global__ void k_bhist(const int* __restrict__ dst, unsigned* __restrict__ bucket_cnt,
                        int E) {
    __shared__ unsigned h[512];
    int t = threadIdx.x;
    h[t] = 0; h[t + 256] = 0;
    __syncthreads();
    int stride = gridDim.x * blockDim.x;
    for (int e = blockIdx.x * blockDim.x + t; e < E; e += stride)
        atomicAdd(&h[(unsigned)dst[e] >> 10], 1u);
    __syncthreads();
    if (h[t]) atomicAdd(&bucket_cnt[t], h[t]);
    if (h[t + 256]) atomicAdd(&bucket_cnt[t + 256], h[t + 256]);
}

__global__ void k_bscan(const unsigned* __restrict__ bucket_cnt,
                        unsigned* __restrict__ bbase, unsigned* __restrict__ bcur, int B) {
    __shared__ unsigned s[512];
    int t = threadIdx.x;
    unsigned v = (t < B) ? bucket_cnt[t] : 0u;
    s[t] = v;
    __syncthreads();
    for (int off = 1; off < 512; off <<= 1) {
        unsigned u = (t >= off) ? s[t - off] : 0u;
        __syncthreads();
        s[t] += u;
        __syncthreads();
    }
    unsigned excl = s[t] - v;
    if (t < B) { bbase[t] = excl; bcur[t] = excl; }
    if (t == B - 1) bbase[B] = s[t];
}

__global__ __launch_bounds__(1024) void k_bscatter2(
        const int* __restrict__ src, const int* __restrict__ dst,
        unsigned* __restrict__ bcur, unsigned* __restrict__ pairs,
        int E, int nblocks) {
    __shared__ unsigned cnt[512];
    int t = threadIdx.x;
    int per = (E + nblocks - 1) / nblocks;
    int beg = blockIdx.x * per;
    int end = beg + per; if (end > E) end = E;
    if (beg >= E) return;
    if (t < 512) cnt[t] = 0;
    __syncthreads();
    for (int e = beg + t; e < end; e += 1024)
        atomicAdd(&cnt[(unsigned)dst[e] >> 10], 1u);
    __syncthreads();
    unsigned c = 0, base = 0;
    if (t < 512) { c = cnt[t]; if (c) base = atomicAdd(&bcur[t], c); }
    __syncthreads();
    if (t < 512) cnt[t] = base;
    __syncthreads();
    for (int e = beg + t; e < end; e += 1024) {
        unsigned d = (unsigned)dst[e];
        unsigned pos = atomicAdd(&cnt[d >> 10], 1u);
        pairs[pos] = ((unsigned)src[e] << 10) | (d & 1023u);
    }
}

// k_p2: per-bucket node sort -> edges (src-only when packed=0) + row_start CSR
__global__ __launch_bounds__(1024) void k_p2(
        const unsigned* __restrict__ pairs, const unsigned* __restrict__ bbase,
        unsigned* __restrict__ edges, unsigned* __restrict__ row_start,
        int N, int B, int E, int packed) {
    __shared__ unsigned cnt[1024], scn[1024], cur[1024];
    int t = threadIdx.x, b = blockIdx.x;
    unsigned beg = bbase[b], end = bbase[b + 1];
    cnt[t] = 0;
    __syncthreads();
    for (unsigned e = beg + t; e < end; e += 1024)
        atomicAdd(&cnt[pairs[e] & 1023u], 1u);
    __syncthreads();
    unsigned v = cnt[t];
    scn[t] = v;
    __syncthreads();
    for (int off = 1; off < 1024; off <<= 1) {
        unsigned u = (t >= off) ? scn[t - off] : 0u;
        __syncthreads();
        scn[t] += u;
        __syncthreads();
    }
    unsigned excl = scn[t] - v;
    int node = (b << 10) + t;
    if (node < N) row_start[node] = beg + excl;
    if (b == B - 1 && t == 0) row_start[N] = (unsigned)E;
    cur[t] = beg + excl;
    __syncthreads();
    for (unsigned e = beg + t; e < end; e += 1024) {
        unsigned pv = pairs[e];
        unsigned pos = atomicAdd(&cur[pv & 1023u], 1u);
        edges[pos] = packed ? pv : (pv >> 10);
    }
}

// =================== R9 hot phase: node-parallel fused layer (bf16 rows) ===================
// One thread per node: serial gather-sum over its CSR range (2x unrolled ->
// 4 row-loads in flight), then the full MLP + graph-sum + next-layer y write.
__global__ __launch_bounds__(256) void k_layerB(
        const unsigned* __restrict__ yin, unsigned* __restrict__ yout,
        const unsigned* __restrict__ row_start, const unsigned* __restrict__ edges,
        const float* __restrict__ b1, const float* __restrict__ W2,
        const float* __restrict__ b2, const float* __restrict__ l,
        const float* __restrict__ W1n,
        const int* __restrict__ node_graph, float* __restrict__ gacc,
        int N, int last) {
    __shared__ float sW2[100], sW1[100], sb1[10], sb2[10], sl[10];
    int t = threadIdx.x;
    if (t < 100) sW2[t] = W2[t];
    if (!last && t >= 128 && t < 228) sW1[t - 128] = W1n[t - 128];
    if (t < 10) { sb1[t] = b1[t]; sb2[t] = b2[t]; sl[t] = l[t]; }
    __syncthreads();
    int n = blockIdx.x * 256 + t;
    bool valid = n < N;
    int nc = valid ? n : (N - 1);
    const unsigned* yr = yin + (size_t)nc * 8;
    uint4 qa = *(const uint4*)yr;
    uint4 qb = *(const uint4*)(yr + 4);   // row is 8 uints; [4..7], only [4] used
    float acc[10] = {bflo(qa.x), bfhi(qa.x), bflo(qa.y), bfhi(qa.y),
                     bflo(qa.z), bfhi(qa.z), bflo(qa.w), bfhi(qa.w),
                     bflo(qb.x), bfhi(qb.x)};

    unsigned beg = 0, end = 0;
    if (valid) { beg = row_start[n]; end = row_start[n + 1]; }
    unsigned e = beg;
    for (; e + 2 <= end; e += 2) {
        unsigned s0 = edges[e];
        unsigned s1 = edges[e + 1];
        const unsigned* p0 = yin + (size_t)s0 * 8;
        const unsigned* p1 = yin + (size_t)s1 * 8;
        uint4 a0 = *(const uint4*)p0;
        uint4 b0 = *(const uint4*)(p0 + 4);
        uint4 a1 = *(const uint4*)p1;
        uint4 b1v = *(const uint4*)(p1 + 4);
        acc[0] += bflo(a0.x) + bflo(a1.x);
        acc[1] += bfhi(a0.x) + bfhi(a1.x);
        acc[2] += bflo(a0.y) + bflo(a1.y);
        acc[3] += bfhi(a0.y) + bfhi(a1.y);
        acc[4] += bflo(a0.z) + bflo(a1.z);
        acc[5] += bfhi(a0.z) + bfhi(a1.z);
        acc[6] += bflo(a0.w) + bflo(a1.w);
        acc[7] += bfhi(a0.w) + bfhi(a1.w);
        acc[8] += bflo(b0.x) + bflo(b1v.x);
        acc[9] += bfhi(b0.x) + bfhi(b1v.x);
    }
    if (e < end) {
        unsigned s0 = edges[e];
        const unsigned* p0 = yin + (size_t)s0 * 8;
        uint4 a0 = *(const uint4*)p0;
        uint4 b0 = *(const uint4*)(p0 + 4);
        acc[0] += bflo(a0.x); acc[1] += bfhi(a0.x);
        acc[2] += bflo(a0.y); acc[3] += bfhi(a0.y);
        acc[4] += bflo(a0.z); acc[5] += bfhi(a0.z);
        acc[6] += bflo(a0.w); acc[7] += bfhi(a0.w);
        acc[8] += bflo(b0.x); acc[9] += bfhi(b0.x);
    }

    float z[10], x[10];
#pragma unroll
    for (int j = 0; j < 10; j++) {
        float v = acc[j] + sb1[j];
        z[j] = v > 0.f ? v : 0.f;
    }
#pragma unroll
    for (int j = 0; j < 10; j++) {
        float v = sb2[j];
#pragma unroll
        for (int k = 0; k < 10; k++) v += z[k] * sW2[k * 10 + j];
        x[j] = v > 0.f ? v : 0.f;
    }
    float p = 0.f;
#pragma unroll
    for (int j = 0; j < 10; j++) p += x[j] * sl[j];
    if (!valid) p = 0.f;
    int g = node_graph[nc];

    int g0 = __shfl(g, 0);
    if (__all(g == g0)) {
#pragma unroll
        for (int off = 32; off > 0; off >>= 1) p += __shfl_down(p, off);
        if ((t & 63) == 0) unsafeAtomicAdd(&gacc[g0], p);
    } else {
        if (valid) unsafeAtomicAdd(&gacc[g], p);
    }

    if (!last && valid) {
        float yn[10];
#pragma unroll
        for (int j = 0; j < 10; j++) {
            float v = 0.f;
#pragma unroll
            for (int k = 0; k < 10; k++) v += x[k] * sW1[k * 10 + j];
            yn[j] = v;
        }
        unsigned r0 = (unsigned)f2bf(yn[0]) | ((unsigned)f2bf(yn[1]) << 16);
        unsigned r1 = (unsigned)f2bf(yn[2]) | ((unsigned)f2bf(yn[3]) << 16);
        unsigned r2 = (unsigned)f2bf(yn[4]) | ((unsigned)f2bf(yn[5]) << 16);
        unsigned r3 = (unsigned)f2bf(yn[6]) | ((unsigned)f2bf(yn[7]) << 16);
        unsigned r4 = (unsigned)f2bf(yn[8]) | ((unsigned)f2bf(yn[9]) << 16);
        unsigned* yo = yout + (size_t)n * 8;
        *(uint4*)yo = make_uint4(r0, r1, r2, r3);
        yo[4] = r4;
    }
}

// ---------------- Final: out[g] = sigmoid(gacc[g] / max(count,1)) ----------------
__global__ void k4_final(const float* __restrict__ gacc, const int* __restrict__ node_graph,
                         float* __restrict__ out, int N, int G) {
    int g = blockIdx.x * blockDim.x + threadIdx.x;
    if (g >= G) return;
    int lo = 0, hi = N;
    while (lo < hi) { int m = (lo + hi) >> 1; if (node_graph[m] < g) lo = m + 1; else hi = m; }
    int lo2 = lo, hi2 = N;
    while (lo2 < hi2) { int m = (lo2 + hi2) >> 1; if (node_graph[m] <= g) lo2 = m + 1; else hi2 = m; }
    float c = (float)(hi2 - lo);
    if (c < 1.f) c = 1.f;
    float s = gacc[g] / c;
    out[g] = 1.f / (1.f + __expf(-s));
}

// ============ R4 fallback fused layer (f32 rows, src-only edges) ============
__global__ __launch_bounds__(256) void k_layer(
        const float* __restrict__ yin, float* __restrict__ yout,
        const unsigned* __restrict__ row_start, const unsigned* __restrict__ edges,
        const float* __restrict__ b1, const float* __restrict__ W2,
        const float* __restrict__ b2, const float* __restrict__ l,
        const float* __restrict__ W1n,
        const int* __restrict__ node_graph, float* __restrict__ gacc,
        int N, int last) {
    __shared__ float sW2[100], sW1[100], sb1[10], sb2[10], sl[10];
    int t = threadIdx.x;
    if (t < 100) sW2[t] = W2[t];
    if (!last && t >= 128 && t < 228) sW1[t - 128] = W1n[t - 128];
    if (t < 10) { sb1[t] = b1[t]; sb2[t] = b2[t]; sl[t] = l[t]; }
    __syncthreads();
    int n = blockIdx.x * 256 + t;
    bool valid = n < N;
    int nc = valid ? n : (N - 1);
    const float* yr = yin + (size_t)nc * 16;
    float4 a = *(const float4*)yr;
    float4 b = *(const float4*)(yr + 4);
    float2 c = *(const float2*)(yr + 8);
    float acc[10] = {a.x, a.y, a.z, a.w, b.x, b.y, b.z, b.w, c.x, c.y};
    unsigned beg = 0, end = 0;
    if (valid) { beg = row_start[n]; end = row_start[n + 1]; }
    for (unsigned e = beg; e < end; ++e) {
        unsigned s = edges[e];
        const float* pr = yin + (size_t)s * 16;
        float4 pa = *(const float4*)pr;
        float4 pb = *(const float4*)(pr + 4);
        float2 pc = *(const float2*)(pr + 8);
        acc[0] += pa.x; acc[1] += pa.y; acc[2] += pa.z; acc[3] += pa.w;
        acc[4] += pb.x; acc[5] += pb.y; acc[6] += pb.z; acc[7] += pb.w;
        acc[8] += pc.x; acc[9] += pc.y;
    }
    float z[10], x[10];
#pragma unroll
    for (int j = 0; j < 10; j++) {
        float v = acc[j] + sb1[j];
        z[j] = v > 0.f ? v : 0.f;
    }
#pragma unroll
    for (int j = 0; j < 10; j++) {
        float v = sb2[j];
#pragma unroll
        for (int k = 0; k < 10; k++) v += z[k] * sW2[k * 10 + j];
        x[j] = v > 0.f ? v : 0.f;
    }
    float p = 0.f;
#pragma unroll
    for (int j = 0; j < 10; j++) p += x[j] * sl[j];
    if (!valid) p = 0.f;
    int g = node_graph[nc];
    int g0 = __shfl(g, 0);
    if (__all(g == g0)) {
#pragma unroll
        for (int off = 32; off > 0; off >>= 1) p += __shfl_down(p, off);
        if ((t & 63) == 0) unsafeAtomicAdd(&gacc[g0], p);
    } else {
        if (valid) unsafeAtomicAdd(&gacc[g], p);
    }
    if (!last && valid) {
        float yn[10];
#pragma unroll
        for (int j = 0; j < 10; j++) {
            float v = 0.f;
#pragma unroll
            for (int k = 0; k < 10; k++) v += x[k] * sW1[k * 10 + j];
            yn[j] = v;
        }
        float* yo = yout + (size_t)n * 16;
        *(float4*)yo = make_float4(yn[0], yn[1], yn[2], yn[3]);
        *(float4*)(yo + 4) = make_float4(yn[4], yn[5], yn[6], yn[7]);
        *(float2*)(yo + 8) = make_float2(yn[8], yn[9]);
    }
}

static inline size_t al16(size_t w) { return (w + 15) & ~(size_t)15; }

extern "C" void kernel_launch(void* const* d_in, const int* in_sizes, int n_in,
                              void* d_out, int out_size, void* d_ws, size_t ws_size,
                              hipStream_t stream) {
    const float* h  = (const float*)d_in[0];
    const int* src  = (const int*)d_in[1];
    const int* dst  = (const int*)d_in[2];
    const int* ng   = (const int*)d_in[3];
    int N = in_sizes[3];
    int E = in_sizes[1];
    int G = out_size;

    const float* W1[5]; const float* b1[5]; const float* W2[5]; const float* b2[5]; const float* l[5];
    for (int i = 0; i < 5; i++) {
        W1[i] = (const float*)d_in[4 + i * 5 + 0];
        b1[i] = (const float*)d_in[4 + i * 5 + 1];
        W2[i] = (const float*)d_in[4 + i * 5 + 2];
        b2[i] = (const float*)d_in[4 + i * 5 + 3];
        l[i]  = (const float*)d_in[4 + i * 5 + 4];
    }
    float* out = (float*)d_out;

    int B = (N + 1023) >> 10;

    // R9 layout (4B words): y0[N*8] | reg2 = max(pairs[E], y1[N*8]) | edges[E]
    //                       | row_start[N+1] | buckets(1537) | gacc[G]
    // pairs dead after k_p2 -> y1 aliases it (same trick as R7).
    size_t wY   = al16((size_t)N * 8);
    size_t wRg2 = al16(((size_t)E > (size_t)N * 8) ? (size_t)E : (size_t)N * 8);
    size_t wE   = al16((size_t)E);
    size_t wRS  = al16((size_t)N + 1);
    size_t need_r9 = (wY + wRg2 + wE + wRS + 1552 + al16((size_t)G)) * 4;

    size_t regAB = (size_t)N * 16;
    size_t reg2f = ((size_t)E > regAB) ? (size_t)E : regAB;
    size_t need_r4 = (regAB + reg2f + (size_t)E + (size_t)(N + 1) + 1537 + (size_t)G) * 4;

    if (ws_size >= need_r9 && B <= 512) {
        unsigned* y0 = (unsigned*)d_ws;
        unsigned* pairs = y0 + wY;
        unsigned* y1 = pairs;              // pairs dead after k_p2
        unsigned* edges = pairs + wRg2;
        unsigned* row_start = edges + wE;
        unsigned* bucket_cnt = row_start + wRS;
        unsigned* bbase = bucket_cnt + 512;
        unsigned* bcur = bbase + 513;
        float* gacc = (float*)(bcur + 512);

        hipMemsetAsync(bucket_cnt, 0, 512 * 4, stream);
        hipMemsetAsync(gacc, 0, (size_t)G * 4, stream);

        k1_hw1_bf16<<<(N + 255) / 256, 256, 0, stream>>>(h, W1[0], y0, N);

        k_bhist<<<2048, 256, 0, stream>>>(dst, bucket_cnt, E);
        k_bscan<<<1, 512, 0, stream>>>(bucket_cnt, bbase, bcur, B);
        k_bscatter2<<<256, 1024, 0, stream>>>(src, dst, bcur, pairs, E, 256);
        k_p2<<<B, 1024, 0, stream>>>(pairs, bbase, edges, row_start, N, B, E, 0);

        unsigned* ybuf[2] = {y0, y1};
        for (int i = 0; i < 5; i++) {
            k_layerB<<<(N + 255) / 256, 256, 0, stream>>>(
                ybuf[i & 1], ybuf[(i + 1) & 1], row_start, edges,
                b1[i], W2[i], b2[i], l[i], i < 4 ? W1[i + 1] : nullptr,
                ng, gacc, N, i == 4 ? 1 : 0);
        }
        k4_final<<<(G + 255) / 256, 256, 0, stream>>>(gacc, ng, out, N, G);
        return;
    }

    // fallback: R4 path (f32 rows, fused node-parallel layer over full CSR)
    if (ws_size >= need_r4 && B <= 512) {
        float* y0 = (float*)d_ws;
        unsigned* pairs = (unsigned*)(y0 + regAB);
        float* y1 = (float*)pairs;
        unsigned* edges = pairs + reg2f;
        unsigned* row_start = edges + E;
        unsigned* bucket_cnt = row_start + (N + 1);
        unsigned* bbase = bucket_cnt + 512;
        unsigned* bcur = bbase + 513;
        float* gacc = (float*)(bcur + 512);

        hipMemsetAsync(bucket_cnt, 0, 512 * 4, stream);
        hipMemsetAsync(gacc, 0, (size_t)G * 4, stream);

        k1_hw1_f32<<<(N + 255) / 256, 256, 0, stream>>>(h, W1[0], y0, N);
        k_bhist<<<2048, 256, 0, stream>>>(dst, bucket_cnt, E);
        k_bscan<<<1, 512, 0, stream>>>(bucket_cnt, bbase, bcur, B);
        k_bscatter2<<<256, 1024, 0, stream>>>(src, dst, bcur, pairs, E, 256);
        k_p2<<<B, 1024, 0, stream>>>(pairs, bbase, edges, row_start, N, B, E, 0);

        float* ybuf[2] = {y0, y1};
        for (int i = 0; i < 5; i++) {
            k_layer<<<(N + 255) / 256, 256, 0, stream>>>(
                ybuf[i & 1], ybuf[(i + 1) & 1], row_start, edges,
                b1[i], W2[i], b2[i], l[i], i < 4 ? W1[i + 1] : nullptr,
                ng, gacc, N, i == 4 ? 1 : 0);
        }
        k4_final<<<(G + 255) / 256, 256, 0, stream>>>(gacc, ng, out, N, G);
    }
}

// Round 3
// 1987.415 us; speedup vs baseline: 2.5237x; 1.4235x over previous
//
#include <hip/hip_runtime.h>

// GIN: 5 layers, DIM=10. Identity: (x+agg)@W1 = x@W1 + segsum((x@W1)[src]).
// R10: quad-per-node fused layer over dst-sorted CSR, bf16 rows.
//  - R8 lesson: LDS atomics ~3.3 cy/lane-op -> never on hot path.
//  - R9 lesson: thread-per-node serial gather = latency-bound (VALU 4%,
//    occ 29%, 440us). Fix: 4 lanes/node -> kA's fully-parallel gather issue
//    pattern, but only 20 shfl_xor per node to combine (vs kA's ~70 bpermute
//    + scan VALU per 128 edges). Zero hot-phase atomics, no carries.

#define SENTINEL 0xFFFFFFFFu

__device__ __forceinline__ unsigned short f2bf(float f) {
    unsigned b = __float_as_uint(f);
    b += 0x7fffu + ((b >> 16) & 1u);   // round-to-nearest-even
    return (unsigned short)(b >> 16);
}
__device__ __forceinline__ float bflo(unsigned u) { return __uint_as_float(u << 16); }
__device__ __forceinline__ float bfhi(unsigned u) { return __uint_as_float(u & 0xffff0000u); }

// ---------------- Layer-1: y = h @ W1_1 (bf16 rows, 8 uints/row) ----------------
__global__ void k1_hw1_bf16(const float* __restrict__ h, const float* __restrict__ W1,
                            unsigned* __restrict__ y, int N) {
    __shared__ float sW[640];
    for (int i = threadIdx.x; i < 640; i += blockDim.x) sW[i] = W1[i];
    __syncthreads();
    int n = blockIdx.x * blockDim.x + threadIdx.x;
    if (n >= N) return;
    const float* hr = h + (size_t)n * 64;
    float acc[10];
#pragma unroll
    for (int j = 0; j < 10; j++) acc[j] = 0.f;
#pragma unroll 4
    for (int k = 0; k < 64; k += 4) {
        float4 hv = *(const float4*)(hr + k);
#pragma unroll
        for (int j = 0; j < 10; j++) {
            acc[j] += hv.x * sW[(k + 0) * 10 + j];
            acc[j] += hv.y * sW[(k + 1) * 10 + j];
            acc[j] += hv.z * sW[(k + 2) * 10 + j];
            acc[j] += hv.w * sW[(k + 3) * 10 + j];
        }
    }
    unsigned r0 = (unsigned)f2bf(acc[0]) | ((unsigned)f2bf(acc[1]) << 16);
    unsigned r1 = (unsigned)f2bf(acc[2]) | ((unsigned)f2bf(acc[3]) << 16);
    unsigned r2 = (unsigned)f2bf(acc[4]) | ((unsigned)f2bf(acc[5]) << 16);
    unsigned r3 = (unsigned)f2bf(acc[6]) | ((unsigned)f2bf(acc[7]) << 16);
    unsigned r4 = (unsigned)f2bf(acc[8]) | ((unsigned)f2bf(acc[9]) << 16);
    unsigned* yr = y + (size_t)n * 8;
    *(uint4*)yr = make_uint4(r0, r1, r2, r3);
    yr[4] = r4;
}

// f32 variant for the fallback path (16-float rows)
__global__ void k1_hw1_f32(const float* __restrict__ h, const float* __restrict__ W1,
                           float* __restrict__ y, int N) {
    __shared__ float sW[640];
    for (int i = threadIdx.x; i < 640; i += blockDim.x) sW[i] = W1[i];
    __syncthreads();
    int n = blockIdx.x * blockDim.x + threadIdx.x;
    if (n >= N) return;
    const float* hr = h + (size_t)n * 64;
    float acc[10];
#pragma unroll
    for (int j = 0; j < 10; j++) acc[j] = 0.f;
#pragma unroll 4
    for (int k = 0; k < 64; k += 4) {
        float4 hv = *(const float4*)(hr + k);
#pragma unroll
        for (int j = 0; j < 10; j++) {
            acc[j] += hv.x * sW[(k + 0) * 10 + j];
            acc[j] += hv.y * sW[(k + 1) * 10 + j];
            acc[j] += hv.z * sW[(k + 2) * 10 + j];
            acc[j] += hv.w * sW[(k + 3) * 10 + j];
        }
    }
    float* yr = y + (size_t)n * 16;
#pragma unroll
    for (int j = 0; j < 10; j++) yr[j] = acc[j];
}

// =================== CSR build: bucket split (dst>>10, 512 buckets) ===================
__global__ void k_bhist(const int* __restrict__ dst, unsigned* __restrict__ bucket_cnt,
                        int E) {
    __shared__ unsigned h[512];
    int t = threadIdx.x;
    h[t] = 0; h[t + 256] = 0;
    __syncthreads();
    int stride = gridDim.x * blockDim.x;
    for (int e = blockIdx.x * blockDim.x + t; e < E; e += stride)
        atomicAdd(&h[(unsigned)dst[e] >> 10], 1u);
    __syncthreads();
    if (h[t]) atomicAdd(&bucket_cnt[t], h[t]);
    if (h[t + 256]) atomicAdd(&bucket_cnt[t + 256], h[t + 256]);
}

__global__ void k_bscan(const unsigned* __restrict__ bucket_cnt,
                        unsigned* __restrict__ bbase, unsigned* __restrict__ bcur, int B) {
    __shared__ unsigned s[512];
    int t = threadIdx.x;
    unsigned v = (t < B) ? bucket_cnt[t] : 0u;
    s[t] = v;
    __syncthreads();
    for (int off = 1; off < 512; off <<= 1) {
        unsigned u = (t >= off) ? s[t - off] : 0u;
        __syncthreads();
        s[t] += u;
        __syncthreads();
    }
    unsigned excl = s[t] - v;
    if (t < B) { bbase[t] = excl; bcur[t] = excl; }
    if (t == B - 1) bbase[B] = s[t];
}

__global__ __launch_bounds__(1024) void k_bscatter2(
        const int* __restrict__ src, const int* __restrict__ dst,
        unsigned* __restrict__ bcur, unsigned* __restrict__ pairs,
        int E, int nblocks) {
    __shared__ unsigned cnt[512];
    int t = threadIdx.x;
    int per = (E + nblocks - 1) / nblocks;
    int beg = blockIdx.x * per;
    int end = beg + per; if (end > E) end = E;
    if (beg >= E) return;
    if (t < 512) cnt[t] = 0;
    __syncthreads();
    for (int e = beg + t; e < end; e += 1024)
        atomicAdd(&cnt[(unsigned)dst[e] >> 10], 1u);
    __syncthreads();
    unsigned c = 0, base = 0;
    if (t < 512) { c = cnt[t]; if (c) base = atomicAdd(&bcur[t], c); }
    __syncthreads();
    if (t < 512) cnt[t] = base;
    __syncthreads();
    for (int e = beg + t; e < end; e += 1024) {
        unsigned d = (unsigned)dst[e];
        unsigned pos = atomicAdd(&cnt[d >> 10], 1u);
        pairs[pos] = ((unsigned)src[e] << 10) | (d & 1023u);
    }
}

// k_p2: per-bucket node sort -> edges (src-only when packed=0) + row_start CSR
__global__ __launch_bounds__(1024) void k_p2(
        const unsigned* __restrict__ pairs, const unsigned* __restrict__ bbase,
        unsigned* __restrict__ edges, unsigned* __restrict__ row_start,
        int N, int B, int E, int packed) {
    __shared__ unsigned cnt[1024], scn[1024], cur[1024];
    int t = threadIdx.x, b = blockIdx.x;
    unsigned beg = bbase[b], end = bbase[b + 1];
    cnt[t] = 0;
    __syncthreads();
    for (unsigned e = beg + t; e < end; e += 1024)
        atomicAdd(&cnt[pairs[e] & 1023u], 1u);
    __syncthreads();
    unsigned v = cnt[t];
    scn[t] = v;
    __syncthreads();
    for (int off = 1; off < 1024; off <<= 1) {
        unsigned u = (t >= off) ? scn[t - off] : 0u;
        __syncthreads();
        scn[t] += u;
        __syncthreads();
    }
    unsigned excl = scn[t] - v;
    int node = (b << 10) + t;
    if (node < N) row_start[node] = beg + excl;
    if (b == B - 1 && t == 0) row_start[N] = (unsigned)E;
    cur[t] = beg + excl;
    __syncthreads();
    for (unsigned e = beg + t; e < end; e += 1024) {
        unsigned pv = pairs[e];
        unsigned pos = atomicAdd(&cur[pv & 1023u], 1u);
        edges[pos] = packed ? pv : (pv >> 10);
    }
}

// =================== R10 hot phase: quad-per-node fused layer (bf16 rows) ===================
// 4 lanes per node: lanes gather edges beg+q, beg+q+4, ... (2x unrolled -> up to
// 4 independent 32B row gathers in flight per lane), combine with 2 shfl_xor
// rounds (20 shuffles/node), all 4 lanes run the MLP redundantly (p identical
// within quad -> wave-sum * 0.25 for the graph atomic), q==0 writes y_next.
__global__ __launch_bounds__(256) void k_layerQ(
        const unsigned* __restrict__ yin, unsigned* __restrict__ yout,
        const unsigned* __restrict__ row_start, const unsigned* __restrict__ edges,
        const float* __restrict__ b1, const float* __restrict__ W2,
        const float* __restrict__ b2, const float* __restrict__ l,
        const float* __restrict__ W1n,
        const int* __restrict__ node_graph, float* __restrict__ gacc,
        int N, int last) {
    __shared__ float sW2[100], sW1[100], sb1[10], sb2[10], sl[10];
    int t = threadIdx.x;
    if (t < 100) sW2[t] = W2[t];
    if (!last && t >= 128 && t < 228) sW1[t - 128] = W1n[t - 128];
    if (t < 10) { sb1[t] = b1[t]; sb2[t] = b2[t]; sl[t] = l[t]; }
    __syncthreads();
    int q = t & 3;
    int n = blockIdx.x * 64 + (t >> 2);
    bool valid = n < N;
    int nc = valid ? n : (N - 1);

    float acc[10];
#pragma unroll
    for (int j = 0; j < 10; j++) acc[j] = 0.f;

    unsigned beg = 0, end = 0;
    if (valid) { beg = row_start[n]; end = row_start[n + 1]; }
    unsigned e = beg + (unsigned)q;
    // 2x unroll: this lane's edges are beg+q, beg+q+4, ... (stride 4)
    for (; e + 4 < end; e += 8) {
        unsigned s0 = edges[e];
        unsigned s1 = edges[e + 4];
        const unsigned* p0 = yin + (size_t)s0 * 8;
        const unsigned* p1 = yin + (size_t)s1 * 8;
        uint4 a0 = *(const uint4*)p0;
        unsigned b0 = p0[4];
        uint4 a1 = *(const uint4*)p1;
        unsigned b1v = p1[4];
        acc[0] += bflo(a0.x) + bflo(a1.x);
        acc[1] += bfhi(a0.x) + bfhi(a1.x);
        acc[2] += bflo(a0.y) + bflo(a1.y);
        acc[3] += bfhi(a0.y) + bfhi(a1.y);
        acc[4] += bflo(a0.z) + bflo(a1.z);
        acc[5] += bfhi(a0.z) + bfhi(a1.z);
        acc[6] += bflo(a0.w) + bflo(a1.w);
        acc[7] += bfhi(a0.w) + bfhi(a1.w);
        acc[8] += bflo(b0)   + bflo(b1v);
        acc[9] += bfhi(b0)   + bfhi(b1v);
    }
    if (e < end) {
        unsigned s0 = edges[e];
        const unsigned* p0 = yin + (size_t)s0 * 8;
        uint4 a0 = *(const uint4*)p0;
        unsigned b0 = p0[4];
        acc[0] += bflo(a0.x); acc[1] += bfhi(a0.x);
        acc[2] += bflo(a0.y); acc[3] += bfhi(a0.y);
        acc[4] += bflo(a0.z); acc[5] += bfhi(a0.z);
        acc[6] += bflo(a0.w); acc[7] += bfhi(a0.w);
        acc[8] += bflo(b0);   acc[9] += bfhi(b0);
    }

    // quad combine: after 2 butterfly rounds all 4 lanes hold the full sum
#pragma unroll
    for (int j = 0; j < 10; j++) acc[j] += __shfl_xor(acc[j], 1);
#pragma unroll
    for (int j = 0; j < 10; j++) acc[j] += __shfl_xor(acc[j], 2);

    // self term (same address across the quad -> broadcast, L1-resident)
    const unsigned* yr = yin + (size_t)nc * 8;
    uint4 qa = *(const uint4*)yr;
    unsigned q4 = yr[4];
    acc[0] += bflo(qa.x); acc[1] += bfhi(qa.x);
    acc[2] += bflo(qa.y); acc[3] += bfhi(qa.y);
    acc[4] += bflo(qa.z); acc[5] += bfhi(qa.z);
    acc[6] += bflo(qa.w); acc[7] += bfhi(qa.w);
    acc[8] += bflo(q4);   acc[9] += bfhi(q4);

    float z[10], x[10];
#pragma unroll
    for (int j = 0; j < 10; j++) {
        float v = acc[j] + sb1[j];
        z[j] = v > 0.f ? v : 0.f;
    }
#pragma unroll
    for (int j = 0; j < 10; j++) {
        float v = sb2[j];
#pragma unroll
        for (int k = 0; k < 10; k++) v += z[k] * sW2[k * 10 + j];
        x[j] = v > 0.f ? v : 0.f;
    }
    float p = 0.f;
#pragma unroll
    for (int j = 0; j < 10; j++) p += x[j] * sl[j];
    if (!valid) p = 0.f;
    int g = node_graph[nc];

    int g0 = __shfl(g, 0);
    if (__all(g == g0)) {
        // every node's p appears in 4 lanes -> wave sum is 4x the true sum
#pragma unroll
        for (int off = 32; off > 0; off >>= 1) p += __shfl_down(p, off);
        if ((t & 63) == 0) unsafeAtomicAdd(&gacc[g0], p * 0.25f);
    } else {
        if (valid && q == 0) unsafeAtomicAdd(&gacc[g], p);
    }

    if (!last && valid && q == 0) {
        float yn[10];
#pragma unroll
        for (int j = 0; j < 10; j++) {
            float v = 0.f;
#pragma unroll
            for (int k = 0; k < 10; k++) v += x[k] * sW1[k * 10 + j];
            yn[j] = v;
        }
        unsigned r0 = (unsigned)f2bf(yn[0]) | ((unsigned)f2bf(yn[1]) << 16);
        unsigned r1 = (unsigned)f2bf(yn[2]) | ((unsigned)f2bf(yn[3]) << 16);
        unsigned r2 = (unsigned)f2bf(yn[4]) | ((unsigned)f2bf(yn[5]) << 16);
        unsigned r3 = (unsigned)f2bf(yn[6]) | ((unsigned)f2bf(yn[7]) << 16);
        unsigned r4 = (unsigned)f2bf(yn[8]) | ((unsigned)f2bf(yn[9]) << 16);
        unsigned* yo = yout + (size_t)n * 8;
        *(uint4*)yo = make_uint4(r0, r1, r2, r3);
        yo[4] = r4;
    }
}

// ---------------- Final: out[g] = sigmoid(gacc[g] / max(count,1)) ----------------
__global__ void k4_final(const float* __restrict__ gacc, const int* __restrict__ node_graph,
                         float* __restrict__ out, int N, int G) {
    int g = blockIdx.x * blockDim.x + threadIdx.x;
    if (g >= G) return;
    int lo = 0, hi = N;
    while (lo < hi) { int m = (lo + hi) >> 1; if (node_graph[m] < g) lo = m + 1; else hi = m; }
    int lo2 = lo, hi2 = N;
    while (lo2 < hi2) { int m = (lo2 + hi2) >> 1; if (node_graph[m] <= g) lo2 = m + 1; else hi2 = m; }
    float c = (float)(hi2 - lo);
    if (c < 1.f) c = 1.f;
    float s = gacc[g] / c;
    out[g] = 1.f / (1.f + __expf(-s));
}

// ============ R4 fallback fused layer (f32 rows, src-only edges) ============
__global__ __launch_bounds__(256) void k_layer(
        const float* __restrict__ yin, float* __restrict__ yout,
        const unsigned* __restrict__ row_start, const unsigned* __restrict__ edges,
        const float* __restrict__ b1, const float* __restrict__ W2,
        const float* __restrict__ b2, const float* __restrict__ l,
        const float* __restrict__ W1n,
        const int* __restrict__ node_graph, float* __restrict__ gacc,
        int N, int last) {
    __shared__ float sW2[100], sW1[100], sb1[10], sb2[10], sl[10];
    int t = threadIdx.x;
    if (t < 100) sW2[t] = W2[t];
    if (!last && t >= 128 && t < 228) sW1[t - 128] = W1n[t - 128];
    if (t < 10) { sb1[t] = b1[t]; sb2[t] = b2[t]; sl[t] = l[t]; }
    __syncthreads();
    int n = blockIdx.x * 256 + t;
    bool valid = n < N;
    int nc = valid ? n : (N - 1);
    const float* yr = yin + (size_t)nc * 16;
    float4 a = *(const float4*)yr;
    float4 b = *(const float4*)(yr + 4);
    float2 c = *(const float2*)(yr + 8);
    float acc[10] = {a.x, a.y, a.z, a.w, b.x, b.y, b.z, b.w, c.x, c.y};
    unsigned beg = 0, end = 0;
    if (valid) { beg = row_start[n]; end = row_start[n + 1]; }
    for (unsigned e = beg; e < end; ++e) {
        unsigned s = edges[e];
        const float* pr = yin + (size_t)s * 16;
        float4 pa = *(const float4*)pr;
        float4 pb = *(const float4*)(pr + 4);
        float2 pc = *(const float2*)(pr + 8);
        acc[0] += pa.x; acc[1] += pa.y; acc[2] += pa.z; acc[3] += pa.w;
        acc[4] += pb.x; acc[5] += pb.y; acc[6] += pb.z; acc[7] += pb.w;
        acc[8] += pc.x; acc[9] += pc.y;
    }
    float z[10], x[10];
#pragma unroll
    for (int j = 0; j < 10; j++) {
        float v = acc[j] + sb1[j];
        z[j] = v > 0.f ? v : 0.f;
    }
#pragma unroll
    for (int j = 0; j < 10; j++) {
        float v = sb2[j];
#pragma unroll
        for (int k = 0; k < 10; k++) v += z[k] * sW2[k * 10 + j];
        x[j] = v > 0.f ? v : 0.f;
    }
    float p = 0.f;
#pragma unroll
    for (int j = 0; j < 10; j++) p += x[j] * sl[j];
    if (!valid) p = 0.f;
    int g = node_graph[nc];
    int g0 = __shfl(g, 0);
    if (__all(g == g0)) {
#pragma unroll
        for (int off = 32; off > 0; off >>= 1) p += __shfl_down(p, off);
        if ((t & 63) == 0) unsafeAtomicAdd(&gacc[g0], p);
    } else {
        if (valid) unsafeAtomicAdd(&gacc[g], p);
    }
    if (!last && valid) {
        float yn[10];
#pragma unroll
        for (int j = 0; j < 10; j++) {
            float v = 0.f;
#pragma unroll
            for (int k = 0; k < 10; k++) v += x[k] * sW1[k * 10 + j];
            yn[j] = v;
        }
        float* yo = yout + (size_t)n * 16;
        *(float4*)yo = make_float4(yn[0], yn[1], yn[2], yn[3]);
        *(float4*)(yo + 4) = make_float4(yn[4], yn[5], yn[6], yn[7]);
        *(float2*)(yo + 8) = make_float2(yn[8], yn[9]);
    }
}

static inline size_t al16(size_t w) { return (w + 15) & ~(size_t)15; }

extern "C" void kernel_launch(void* const* d_in, const int* in_sizes, int n_in,
                              void* d_out, int out_size, void* d_ws, size_t ws_size,
                              hipStream_t stream) {
    const float* h  = (const float*)d_in[0];
    const int* src  = (const int*)d_in[1];
    const int* dst  = (const int*)d_in[2];
    const int* ng   = (const int*)d_in[3];
    int N = in_sizes[3];
    int E = in_sizes[1];
    int G = out_size;

    const float* W1[5]; const float* b1[5]; const float* W2[5]; const float* b2[5]; const float* l[5];
    for (int i = 0; i < 5; i++) {
        W1[i] = (const float*)d_in[4 + i * 5 + 0];
        b1[i] = (const float*)d_in[4 + i * 5 + 1];
        W2[i] = (const float*)d_in[4 + i * 5 + 2];
        b2[i] = (const float*)d_in[4 + i * 5 + 3];
        l[i]  = (const float*)d_in[4 + i * 5 + 4];
    }
    float* out = (float*)d_out;

    int B = (N + 1023) >> 10;

    // R10 layout (4B words): y0[N*8] | reg2 = max(pairs[E], y1[N*8]) | edges[E]
    //                        | row_start[N+1] | buckets(1537) | gacc[G]
    // pairs dead after k_p2 -> y1 aliases it.
    size_t wY   = al16((size_t)N * 8);
    size_t wRg2 = al16(((size_t)E > (size_t)N * 8) ? (size_t)E : (size_t)N * 8);
    size_t wE   = al16((size_t)E);
    size_t wRS  = al16((size_t)N + 1);
    size_t need_r10 = (wY + wRg2 + wE + wRS + 1552 + al16((size_t)G)) * 4;

    size_t regAB = (size_t)N * 16;
    size_t reg2f = ((size_t)E > regAB) ? (size_t)E : regAB;
    size_t need_r4 = (regAB + reg2f + (size_t)E + (size_t)(N + 1) + 1537 + (size_t)G) * 4;

    if (ws_size >= need_r10 && B <= 512) {
        unsigned* y0 = (unsigned*)d_ws;
        unsigned* pairs = y0 + wY;
        unsigned* y1 = pairs;              // pairs dead after k_p2
        unsigned* edges = pairs + wRg2;
        unsigned* row_start = edges + wE;
        unsigned* bucket_cnt = row_start + wRS;
        unsigned* bbase = bucket_cnt + 512;
        unsigned* bcur = bbase + 513;
        float* gacc = (float*)(bcur + 512);

        hipMemsetAsync(bucket_cnt, 0, 512 * 4, stream);
        hipMemsetAsync(gacc, 0, (size_t)G * 4, stream);

        k1_hw1_bf16<<<(N + 255) / 256, 256, 0, stream>>>(h, W1[0], y0, N);

        k_bhist<<<2048, 256, 0, stream>>>(dst, bucket_cnt, E);
        k_bscan<<<1, 512, 0, stream>>>(bucket_cnt, bbase, bcur, B);
        k_bscatter2<<<256, 1024, 0, stream>>>(src, dst, bcur, pairs, E, 256);
        k_p2<<<B, 1024, 0, stream>>>(pairs, bbase, edges, row_start, N, B, E, 0);

        unsigned* ybuf[2] = {y0, y1};
        int qblocks = (N + 63) / 64;
        for (int i = 0; i < 5; i++) {
            k_layerQ<<<qblocks, 256, 0, stream>>>(
                ybuf[i & 1], ybuf[(i + 1) & 1], row_start, edges,
                b1[i], W2[i], b2[i], l[i], i < 4 ? W1[i + 1] : nullptr,
                ng, gacc, N, i == 4 ? 1 : 0);
        }
        k4_final<<<(G + 255) / 256, 256, 0, stream>>>(gacc, ng, out, N, G);
        return;
    }

    // fallback: R4 path (f32 rows, fused node-parallel layer over full CSR)
    if (ws_size >= need_r4 && B <= 512) {
        float* y0 = (float*)d_ws;
        unsigned* pairs = (unsigned*)(y0 + regAB);
        float* y1 = (float*)pairs;
        unsigned* edges = pairs + reg2f;
        unsigned* row_start = edges + E;
        unsigned* bucket_cnt = row_start + (N + 1);
        unsigned* bbase = bucket_cnt + 512;
        unsigned* bcur = bbase + 513;
        float* gacc = (float*)(bcur + 512);

        hipMemsetAsync(bucket_cnt, 0, 512 * 4, stream);
        hipMemsetAsync(gacc, 0, (size_t)G * 4, stream);

        k1_hw1_f32<<<(N + 255) / 256, 256, 0, stream>>>(h, W1[0], y0, N);
        k_bhist<<<2048, 256, 0, stream>>>(dst, bucket_cnt, E);
        k_bscan<<<1, 512, 0, stream>>>(bucket_cnt, bbase, bcur, B);
        k_bscatter2<<<256, 1024, 0, stream>>>(src, dst, bcur, pairs, E, 256);
        k_p2<<<B, 1024, 0, stream>>>(pairs, bbase, edges, row_start, N, B, E, 0);

        float* ybuf[2] = {y0, y1};
        for (int i = 0; i < 5; i++) {
            k_layer<<<(N + 255) / 256, 256, 0, stream>>>(
                ybuf[i & 1], ybuf[(i + 1) & 1], row_start, edges,
                b1[i], W2[i], b2[i], l[i], i < 4 ? W1[i + 1] : nullptr,
                ng, gacc, N, i == 4 ? 1 : 0);
        }
        k4_final<<<(G + 255) / 256, 256, 0, stream>>>(gacc, ng, out, N, G);
    }
}